// Round 1
// baseline (209.318 us; speedup 1.0000x reference)
//
#include <hip/hip_runtime.h>
#include <hip/hip_bf16.h>
#include <cstdint>
#include <cstddef>

#define DEVI static __device__ __forceinline__

typedef short s16x8 __attribute__((ext_vector_type(8)));
typedef float f32x4 __attribute__((ext_vector_type(4)));

DEVI f32x4 mfma16x16(s16x8 a, s16x8 b, f32x4 c) {
  return __builtin_amdgcn_mfma_f32_16x16x32_bf16(a, b, c, 0, 0, 0);
}

// fp32 -> bf16 round-to-nearest-even
DEVI unsigned short f2bf(float f) {
  unsigned u = __builtin_bit_cast(unsigned, f);
  u += 0x7FFFu + ((u >> 16) & 1u);
  return (unsigned short)(u >> 16);
}

DEVI s16x8 ld8(const float* p) {
  const float4* q = (const float4*)p;
  float4 a = q[0], b = q[1];
  s16x8 r;
  r[0] = (short)f2bf(a.x); r[1] = (short)f2bf(a.y);
  r[2] = (short)f2bf(a.z); r[3] = (short)f2bf(a.w);
  r[4] = (short)f2bf(b.x); r[5] = (short)f2bf(b.y);
  r[6] = (short)f2bf(b.z); r[7] = (short)f2bf(b.w);
  return r;
}
DEVI s16x8 ld8(const unsigned short* p) { return *(const s16x8*)p; }

// ---------------------------------------------------------------------------
// C[m][n] = sum_k A[m][k] * B[n][k]   (NT GEMM, bf16 MFMA, fp32 accumulate)
// A: [M][K] (fp32 or bf16), B: [N][K] fp32.
// EPI==0: Cf fp32 [M][N].
// EPI==2: fused qkv split + RoPE epilogue (M = B*S = 4096, N = 3072):
//         cols [0,1024) -> Q (rope, *0.125) -> Qp[bh][s][64]
//         cols [1024,2048) -> K (rope)      -> Kp[bh][s][64]
//         cols [2048,3072) -> V             -> Vp[bh][64][2048] (transposed)
// Tiles: BM=BN=128, BK=64, 256 threads (4 waves, 2x2 of 64x64).
// LDS XOR swizzle (T2): elem ^= (row&7)<<3 on 8-elem chunks -> conflict-free
// ds_read_b128 fragment reads.
// ---------------------------------------------------------------------------
template <typename TA, int EPI>
__global__ __launch_bounds__(256, 2) void gemm_nt(
    const TA* __restrict__ A, const float* __restrict__ B, float* __restrict__ Cf,
    unsigned short* __restrict__ Qp, unsigned short* __restrict__ Kp,
    unsigned short* __restrict__ Vp, int M, int N, int K) {
  __shared__ __align__(16) unsigned short As[128 * 64];
  __shared__ __align__(16) unsigned short Bs[128 * 64];
  const int tid = threadIdx.x;
  const int m0 = blockIdx.y * 128, n0 = blockIdx.x * 128;
  const int wid = tid >> 6, lane = tid & 63;
  const int wm = wid >> 1, wn = wid & 1;
  const int lr = lane & 15, lg = lane >> 4;

  f32x4 acc[4][4] = {};
  const int T = K >> 6;
  s16x8 pa[4], pb[4];

  // prologue: prefetch K-step 0 into registers (convert to bf16 at load)
  #pragma unroll
  for (int j = 0; j < 4; ++j) {
    int c = tid + j * 256, row = c >> 3, cc = c & 7;
    pa[j] = ld8(A + (size_t)(m0 + row) * K + cc * 8);
    pb[j] = ld8(B + (size_t)(n0 + row) * K + cc * 8);
  }

  for (int t = 0; t < T; ++t) {
    __syncthreads();
    #pragma unroll
    for (int j = 0; j < 4; ++j) {
      int c = tid + j * 256, row = c >> 3, cc = c & 7;
      int le = row * 64 + ((cc * 8) ^ ((row & 7) << 3));
      *(s16x8*)&As[le] = pa[j];
      *(s16x8*)&Bs[le] = pb[j];
    }
    __syncthreads();
    if (t + 1 < T) {  // prefetch next K-step; overlaps with MFMA below
      const int k0 = (t + 1) << 6;
      #pragma unroll
      for (int j = 0; j < 4; ++j) {
        int c = tid + j * 256, row = c >> 3, cc = c & 7;
        pa[j] = ld8(A + (size_t)(m0 + row) * K + k0 + cc * 8);
        pb[j] = ld8(B + (size_t)(n0 + row) * K + k0 + cc * 8);
      }
    }
    s16x8 af[4][2], bf[4][2];
    #pragma unroll
    for (int m = 0; m < 4; ++m)
      #pragma unroll
      for (int kk = 0; kk < 2; ++kk) {
        int row = wm * 64 + m * 16 + lr;
        af[m][kk] = *(const s16x8*)&As[row * 64 + ((kk * 32 + lg * 8) ^ ((row & 7) << 3))];
      }
    #pragma unroll
    for (int n = 0; n < 4; ++n)
      #pragma unroll
      for (int kk = 0; kk < 2; ++kk) {
        int row = wn * 64 + n * 16 + lr;
        bf[n][kk] = *(const s16x8*)&Bs[row * 64 + ((kk * 32 + lg * 8) ^ ((row & 7) << 3))];
      }
    #pragma unroll
    for (int kk = 0; kk < 2; ++kk)
      #pragma unroll
      for (int m = 0; m < 4; ++m)
        #pragma unroll
        for (int n = 0; n < 4; ++n)
          acc[m][n] = mfma16x16(af[m][kk], bf[n][kk], acc[m][n]);
  }

  // epilogue  (C/D layout: row = lg*4 + i, col = lr  -- m89-verified)
  if constexpr (EPI == 0) {
    #pragma unroll
    for (int m = 0; m < 4; ++m)
      #pragma unroll
      for (int i = 0; i < 4; ++i) {
        int r = m0 + wm * 64 + m * 16 + lg * 4 + i;
        #pragma unroll
        for (int n = 0; n < 4; ++n)
          Cf[(size_t)r * N + n0 + wn * 64 + n * 16 + lr] = acc[m][n][i];
      }
  } else {
    const int colb = n0 + wn * 64;          // wave's 64-col span = one head
    const int part = colb >> 10;            // 0=q 1=k 2=v (block-uniform)
    const int h = (colb & 1023) >> 6;
    #pragma unroll
    for (int m = 0; m < 4; ++m)
      #pragma unroll
      for (int i = 0; i < 4; ++i) {
        const int r = m0 + wm * 64 + m * 16 + lg * 4 + i;
        const int b = r >> 11, s = r & 2047;
        const size_t bh = (size_t)b * 16 + h;
        if (part == 2) {
          #pragma unroll
          for (int n = 0; n < 4; ++n)
            Vp[(bh * 64 + n * 16 + lr) * 2048 + s] = f2bf(acc[m][n][i]);
        } else {
          // rope pair (d, d+32) lives in (n, n+2) of the same lane
          #pragma unroll
          for (int n = 0; n < 2; ++n) {
            const int d = n * 16 + lr;      // 0..31
            float ang = (float)s * exp2f((float)d * -0.4152410118609203f);
            float c, sn;
            sincosf(ang, &sn, &c);
            float x1 = acc[m][n][i], x2 = acc[m][n + 2][i];
            float o1 = x1 * c - x2 * sn;
            float o2 = x2 * c + x1 * sn;
            unsigned short* dst;
            if (part == 0) { o1 *= 0.125f; o2 *= 0.125f; dst = Qp; }  // fold 1/sqrt(dh)
            else dst = Kp;
            dst[(bh * 2048 + s) * 64 + d] = f2bf(o1);
            dst[(bh * 2048 + s) * 64 + d + 32] = f2bf(o2);
          }
        }
      }
  }
}

// ---------------------------------------------------------------------------
// Causal flash attention.  Qr/Kr: bf16 [BH][S][64] (Q pre-scaled by 1/8),
// VT: bf16 [BH][64][S], Z: bf16 [B*S][1024].
// Block: 4 waves, BQ=128 (32 q-rows per wave), BKV=64.
// Online softmax fully wave-parallel (16-lane shfl_xor reductions).
// ---------------------------------------------------------------------------
__global__ __launch_bounds__(256, 2) void attn_fwd(
    const unsigned short* __restrict__ Qr, const unsigned short* __restrict__ Kr,
    const unsigned short* __restrict__ VT, unsigned short* __restrict__ Z) {
  __shared__ __align__(16) unsigned short Kl[64 * 64];
  __shared__ __align__(16) unsigned short Vl[64 * 64];
  __shared__ __align__(16) unsigned short Pl[4][32 * 64];
  const int tid = threadIdx.x;
  const int bh = blockIdx.x;
  const int h = bh & 15, b = bh >> 4;
  const int yt = blockIdx.y;
  const int qt = (yt < 8) ? (2 * yt) : (31 - 2 * yt);  // pair heavy+light tiles per CU
  const int q0 = qt * 128;
  const int wid = tid >> 6, lane = tid & 63;
  const int lr = lane & 15, lg = lane >> 4;
  const int qw = q0 + wid * 32;

  // Q fragments stay in registers for the whole block
  s16x8 qf[2][2];
  #pragma unroll
  for (int m = 0; m < 2; ++m)
    #pragma unroll
    for (int kk = 0; kk < 2; ++kk)
      qf[m][kk] = *(const s16x8*)&Qr[((size_t)bh * 2048 + qw + m * 16 + lr) * 64 + kk * 32 + lg * 8];

  f32x4 oacc[2][4] = {};
  float mrun[8], lrun[8];
  #pragma unroll
  for (int r = 0; r < 8; ++r) { mrun[r] = -__builtin_inff(); lrun[r] = 0.f; }

  const int ntiles = (q0 >> 6) + 2;
  for (int t = 0; t < ntiles; ++t) {
    const int kv0 = t << 6;
    __syncthreads();
    // stage K tile [64][64] and V^T tile [64][64] (swizzled)
    #pragma unroll
    for (int c = tid; c < 512; c += 256) {
      const int row = c >> 3, cc = c & 7;
      const int le = row * 64 + ((cc * 8) ^ ((row & 7) << 3));
      *(s16x8*)&Kl[le] = *(const s16x8*)&Kr[((size_t)bh * 2048 + kv0 + row) * 64 + cc * 8];
      *(s16x8*)&Vl[le] = *(const s16x8*)&VT[((size_t)bh * 64 + row) * 2048 + kv0 + cc * 8];
    }
    __syncthreads();
    if (kv0 > qw + 31) continue;   // tile fully above causal diag for this wave

    // S = Q K^T  (scale already folded into Q)
    f32x4 sacc[2][4] = {};
    #pragma unroll
    for (int kk = 0; kk < 2; ++kk) {
      s16x8 kf[4];
      #pragma unroll
      for (int n = 0; n < 4; ++n) {
        const int row = n * 16 + lr;
        kf[n] = *(const s16x8*)&Kl[row * 64 + ((kk * 32 + lg * 8) ^ ((row & 7) << 3))];
      }
      #pragma unroll
      for (int m = 0; m < 2; ++m)
        #pragma unroll
        for (int n = 0; n < 4; ++n)
          sacc[m][n] = mfma16x16(qf[m][kk], kf[n], sacc[m][n]);
    }

    // online softmax; each lane owns 8 rows (m*4+i), 4 cols each (n)
    const bool diag = (kv0 + 63) > qw;
    #pragma unroll
    for (int m = 0; m < 2; ++m)
      #pragma unroll
      for (int i = 0; i < 4; ++i) {
        const int ridx = m * 4 + i;
        const int row = m * 16 + lg * 4 + i;   // local q row 0..31
        const int qabs = qw + row;
        float sv[4];
        float mx = -__builtin_inff();
        #pragma unroll
        for (int n = 0; n < 4; ++n) {
          float v = sacc[m][n][i];
          if (diag && (kv0 + n * 16 + lr) > qabs) v = -__builtin_inff();
          sv[n] = v;
          mx = fmaxf(mx, v);
        }
        mx = fmaxf(mx, __shfl_xor(mx, 1));
        mx = fmaxf(mx, __shfl_xor(mx, 2));
        mx = fmaxf(mx, __shfl_xor(mx, 4));
        mx = fmaxf(mx, __shfl_xor(mx, 8));
        const float mnew = fmaxf(mrun[ridx], mx);
        const float alpha = __expf(mrun[ridx] - mnew);
        float rs = 0.f;
        #pragma unroll
        for (int n = 0; n < 4; ++n) {
          const float p = __expf(sv[n] - mnew);
          rs += p;
          Pl[wid][row * 64 + ((n * 16 + lr) ^ ((row & 7) << 3))] = (short)f2bf(p);
        }
        rs += __shfl_xor(rs, 1);
        rs += __shfl_xor(rs, 2);
        rs += __shfl_xor(rs, 4);
        rs += __shfl_xor(rs, 8);
        lrun[ridx] = lrun[ridx] * alpha + rs;
        mrun[ridx] = mnew;
        #pragma unroll
        for (int n = 0; n < 4; ++n) oacc[m][n][i] *= alpha;
      }

    // make own-wave P writes visible before fragment reads (rule 18)
    asm volatile("s_waitcnt lgkmcnt(0)" ::: "memory");
    __builtin_amdgcn_sched_barrier(0);

    // O += P V   (P per-wave in LDS, V^T tile shared)
    #pragma unroll
    for (int kk = 0; kk < 2; ++kk) {
      s16x8 pf[2], vf[4];
      #pragma unroll
      for (int m = 0; m < 2; ++m) {
        const int row = m * 16 + lr;
        pf[m] = *(const s16x8*)&Pl[wid][row * 64 + ((kk * 32 + lg * 8) ^ ((row & 7) << 3))];
      }
      #pragma unroll
      for (int n = 0; n < 4; ++n) {
        const int row = n * 16 + lr;
        vf[n] = *(const s16x8*)&Vl[row * 64 + ((kk * 32 + lg * 8) ^ ((row & 7) << 3))];
      }
      #pragma unroll
      for (int m = 0; m < 2; ++m)
        #pragma unroll
        for (int n = 0; n < 4; ++n)
          oacc[m][n] = mfma16x16(pf[m], vf[n], oacc[m][n]);
    }
  }

  // normalize + write Z[b*S+q][h*64+d] bf16
  #pragma unroll
  for (int m = 0; m < 2; ++m)
    #pragma unroll
    for (int i = 0; i < 4; ++i) {
      const float inv = 1.f / lrun[m * 4 + i];
      const int q = qw + m * 16 + lg * 4 + i;
      const size_t base = ((size_t)b * 2048 + q) * 1024 + h * 64;
      #pragma unroll
      for (int n = 0; n < 4; ++n)
        Z[base + n * 16 + lr] = (short)f2bf(oacc[m][n][i] * inv);
    }
}

// ---------------------------------------------------------------------------
extern "C" void kernel_launch(void* const* d_in, const int* in_sizes, int n_in,
                              void* d_out, int out_size, void* d_ws, size_t ws_size,
                              hipStream_t stream) {
  const float* x     = (const float*)d_in[0];   // [2,2048,1024]
  const float* w_qkv = (const float*)d_in[1];   // [3072,1024]
  const float* w_o   = (const float*)d_in[2];   // [1024,1024]
  float* out = (float*)d_out;                   // [2,2048,1024] fp32

  unsigned short* wsp = (unsigned short*)d_ws;
  unsigned short* Qr = wsp;                     // [32][2048][64] bf16
  unsigned short* Kr = wsp + 4194304;           // [32][2048][64] bf16
  unsigned short* VT = wsp + 8388608;           // [32][64][2048] bf16
  unsigned short* Z  = wsp + 12582912;          // [4096][1024]  bf16
  // total ws use: 32 MiB

  // 1) QKV projection + fused RoPE/split/transpose epilogue
  gemm_nt<float, 2><<<dim3(24, 32), 256, 0, stream>>>(
      x, w_qkv, nullptr, Qr, Kr, VT, 4096, 3072, 1024);

  // 2) causal flash attention
  attn_fwd<<<dim3(32, 16), 256, 0, stream>>>(Qr, Kr, VT, Z);

  // 3) output projection (fp32 out)
  gemm_nt<unsigned short, 0><<<dim3(8, 32), 256, 0, stream>>>(
      Z, w_o, out, nullptr, nullptr, nullptr, 4096, 1024, 1024);
}